// Round 3
// baseline (137.977 us; speedup 1.0000x reference)
//
#include <hip/hip_runtime.h>

#define HH 512
#define WW 512
#define BB 64
#define HW (HH*WW)
#define BGRP 16        // batches per block (4 y-groups)

typedef float v2f __attribute__((ext_vector_type(2)));
typedef float v4f __attribute__((ext_vector_type(4)));

// ---------------------------------------------------------------------------
// Compile-time construction + inversion of the 19x19 TPS system matrix.
// RBF rows pre-scaled by ln(2) so the kernel can use hw v_log_f32 (log2).
// ---------------------------------------------------------------------------
constexpr double cx_ln(double x) {
  int e = 0;
  while (x >= 2.0) { x *= 0.5; ++e; }
  while (x < 1.0)  { x *= 2.0; --e; }
  double z = (x - 1.0) / (x + 1.0);
  double z2 = z * z, term = z, sum = 0.0;
  for (int n = 1; n < 60; n += 2) { sum += term / n; term *= z2; }
  return 2.0 * sum + e * 0.69314718055994530942;
}

struct WMat { float w[19][16]; };

constexpr WMat build_wm() {
  const double Xc[4] = {-1.0, -1.0/3.0, 1.0/3.0, 1.0};
  double A[19][38] = {};
  for (int r = 0; r < 19; ++r) {
    for (int c = 0; c < 38; ++c) {
      double v = 0.0;
      if (c >= 19) {
        v = ((c - 19) == r) ? 1.0 : 0.0;
      } else if (r < 16 && c < 16) {
        double dx = Xc[r >> 2] - Xc[c >> 2];
        double dy = Xc[r & 3] - Xc[c & 3];
        double r2 = dx * dx + dy * dy;
        v = (r2 == 0.0) ? 0.0 : r2 * cx_ln(r2 + 1e-6);
      } else if (r < 16) {
        v = (c == 16) ? 1.0 : ((c == 17) ? Xc[r >> 2] : Xc[r & 3]);
      } else if (c < 16) {
        v = (r == 16) ? 1.0 : ((r == 17) ? Xc[c >> 2] : Xc[c & 3]);
      }
      A[r][c] = v;
    }
  }
  for (int k = 0; k < 19; ++k) {
    int best = k;
    double bv = A[k][k] < 0 ? -A[k][k] : A[k][k];
    for (int r = k + 1; r < 19; ++r) {
      double av = A[r][k] < 0 ? -A[r][k] : A[r][k];
      if (av > bv) { bv = av; best = r; }
    }
    if (best != k)
      for (int c = 0; c < 38; ++c) { double t = A[k][c]; A[k][c] = A[best][c]; A[best][c] = t; }
    double rp = 1.0 / A[k][k];
    for (int c = 0; c < 38; ++c) A[k][c] *= rp;
    for (int r = 0; r < 19; ++r) {
      if (r == k) continue;
      double f = A[r][k];
      for (int c = 0; c < 38; ++c) A[r][c] -= f * A[k][c];
    }
  }
  WMat wm = {};
  for (int i = 0; i < 19; ++i)
    for (int j = 0; j < 16; ++j)
      wm.w[i][j] = (float)(A[i][19 + j] * (i < 16 ? 0.69314718055994530942 : 1.0));
  return wm;
}

__device__ __constant__ WMat WM = build_wm();

__device__ __forceinline__ float fast_log2(float x) {
#if __has_builtin(__builtin_amdgcn_logf)
  return __builtin_amdgcn_logf(x);
#else
  return __log2f(x);
#endif
}

// ---------------------------------------------------------------------------
// Fused kernel, 4 pixels/thread. Stage 1: block's BGRP x 38 coefficients ->
// LDS. Stage 2: batch-independent RBF basis for 4 adjacent pixels (two v2f
// pairs), then the batch loop does 10 ds_read_b128 per 4 pixels (2x better
// amortization than 2 px/thread) + 64 v_pk_fma, two dwordx4 stores.
// ---------------------------------------------------------------------------
__global__ __launch_bounds__(256) void tps_fused_kernel(
    const float* __restrict__ sp, float* __restrict__ out) {
  __shared__ float lc[BGRP][40];   // 40-float row stride -> 16B-aligned rows
  const int b0 = blockIdx.y * BGRP;

  // ---- stage 1: coefficients for this block's batches -> LDS ----
  for (int e = threadIdx.x; e < BGRP * 38; e += 256) {
    const int bi = e / 38;
    const int idx = e - bi * 38;
    const int row = idx >> 1, d = idx & 1;     // coeff row 0..18, dim x/y
    const float* s = sp + (b0 + bi) * 32 + d;
    float acc = 0.0f;
#pragma unroll
    for (int j = 0; j < 16; ++j) acc = fmaf(WM.w[row][j], s[2 * j], acc);
    lc[bi][idx] = acc;
  }

  // ---- batch-independent pixel geometry for 4 adjacent px, same row ----
  const int n0 = (blockIdx.x * 256 + threadIdx.x) * 4;
  const int ix = n0 & (WW - 1);                // n0 % 4 == 0 -> ix+3 <= 511
  const int iy = n0 >> 9;
  const float step = 2.0f / 511.0f;
  const float gy = -1.0f + iy * step;
  const v2f gxa = {-1.0f + ix * step, -1.0f + (ix + 1) * step};
  const v2f gxb = {-1.0f + (ix + 2) * step, -1.0f + (ix + 3) * step};
  const float Xc[4] = {-1.0f, -1.0f / 3.0f, 1.0f / 3.0f, 1.0f};

  float dy2[4];
#pragma unroll
  for (int j = 0; j < 4; ++j) { float t = gy - Xc[j]; dy2[j] = t * t; }

  v2f dxa[4], dxb[4];
#pragma unroll
  for (int i = 0; i < 4; ++i) {
    v2f ta = gxa - Xc[i];
    v2f tb = gxb - Xc[i];
    dxa[i] = ta * ta + 1e-6f;   // eps folded here (dy2 has none)
    dxb[i] = tb * tb + 1e-6f;
  }

  // RBF basis, packed: ua[k] = {u_k(px0), u_k(px1)}, ub[k] = {u_k(px2), u_k(px3)}
  v2f ua[16], ub[16];
#pragma unroll
  for (int k = 0; k < 16; ++k) {
    v2f ta = dxa[k >> 2] + dy2[k & 3];                    // v_pk_add_f32
    v2f tb = dxb[k >> 2] + dy2[k & 3];
    ua[k] = ta * (v2f){fast_log2(ta.x), fast_log2(ta.y)}; // 2 logs + pk_mul
    ub[k] = tb * (v2f){fast_log2(tb.x), fast_log2(tb.y)};
  }

  __syncthreads();

  // ---- stage 2: batch loop, coeffs broadcast-read from LDS ----
  float* op = out + (size_t)((size_t)b0 * HW + n0) * 2;
  for (int bi = 0; bi < BGRP; ++bi) {
    const v4f* c4 = (const v4f*)lc[bi];
    v4f q[10];
#pragma unroll
    for (int i = 0; i < 10; ++i) q[i] = c4[i];          // 10x ds_read_b128, broadcast
#define CQ(i) (q[(i) >> 2][(i) & 3])                    // compile-time reg alias

    v2f axa = CQ(32) + gxa * CQ(34) + gy * CQ(36);
    v2f aya = CQ(33) + gxa * CQ(35) + gy * CQ(37);
    v2f axb = CQ(32) + gxb * CQ(34) + gy * CQ(36);
    v2f ayb = CQ(33) + gxb * CQ(35) + gy * CQ(37);
#pragma unroll
    for (int k = 0; k < 16; ++k) {
      axa += ua[k] * CQ(2 * k);                         // v_pk_fma
      aya += ua[k] * CQ(2 * k + 1);
      axb += ub[k] * CQ(2 * k);
      ayb += ub[k] * CQ(2 * k + 1);
    }
#undef CQ

    v4f va = {axa.x, aya.x, axa.y, aya.y};
    v4f vb = {axb.x, ayb.x, axb.y, ayb.y};
    *(v4f*)op = va;
    *(v4f*)(op + 4) = vb;
    op += (size_t)HW * 2;
  }
}

extern "C" void kernel_launch(void* const* d_in, const int* in_sizes, int n_in,
                              void* d_out, int out_size, void* d_ws, size_t ws_size,
                              hipStream_t stream) {
  const float* sp = (const float*)d_in[0];   // [B, K, 2] fp32
  float* out = (float*)d_out;                // [B, H, W, 2] fp32
  (void)d_ws; (void)ws_size;

  dim3 grid(HW / 1024, BB / BGRP);           // 1024 px per block x, 4 batch-groups y
  tps_fused_kernel<<<grid, 256, 0, stream>>>(sp, out);
}

// Round 4
// 136.095 us; speedup vs baseline: 1.0138x; 1.0138x over previous
//
#include <hip/hip_runtime.h>

#define HH 512
#define WW 512
#define BB 64
#define HW (HH*WW)
#define BGRP 16        // batches per block (4 y-groups)

typedef float v2f __attribute__((ext_vector_type(2)));
typedef float v4f __attribute__((ext_vector_type(4)));

// ---------------------------------------------------------------------------
// Compile-time construction + inversion of the 19x19 TPS system matrix.
// RBF rows pre-scaled by ln(2) so the kernel can use hw v_log_f32 (log2).
// ---------------------------------------------------------------------------
constexpr double cx_ln(double x) {
  int e = 0;
  while (x >= 2.0) { x *= 0.5; ++e; }
  while (x < 1.0)  { x *= 2.0; --e; }
  double z = (x - 1.0) / (x + 1.0);
  double z2 = z * z, term = z, sum = 0.0;
  for (int n = 1; n < 60; n += 2) { sum += term / n; term *= z2; }
  return 2.0 * sum + e * 0.69314718055994530942;
}

struct WMat { float w[19][16]; };

constexpr WMat build_wm() {
  const double Xc[4] = {-1.0, -1.0/3.0, 1.0/3.0, 1.0};
  double A[19][38] = {};
  for (int r = 0; r < 19; ++r) {
    for (int c = 0; c < 38; ++c) {
      double v = 0.0;
      if (c >= 19) {
        v = ((c - 19) == r) ? 1.0 : 0.0;
      } else if (r < 16 && c < 16) {
        double dx = Xc[r >> 2] - Xc[c >> 2];
        double dy = Xc[r & 3] - Xc[c & 3];
        double r2 = dx * dx + dy * dy;
        v = (r2 == 0.0) ? 0.0 : r2 * cx_ln(r2 + 1e-6);
      } else if (r < 16) {
        v = (c == 16) ? 1.0 : ((c == 17) ? Xc[r >> 2] : Xc[r & 3]);
      } else if (c < 16) {
        v = (r == 16) ? 1.0 : ((r == 17) ? Xc[c >> 2] : Xc[c & 3]);
      }
      A[r][c] = v;
    }
  }
  for (int k = 0; k < 19; ++k) {
    int best = k;
    double bv = A[k][k] < 0 ? -A[k][k] : A[k][k];
    for (int r = k + 1; r < 19; ++r) {
      double av = A[r][k] < 0 ? -A[r][k] : A[r][k];
      if (av > bv) { bv = av; best = r; }
    }
    if (best != k)
      for (int c = 0; c < 38; ++c) { double t = A[k][c]; A[k][c] = A[best][c]; A[best][c] = t; }
    double rp = 1.0 / A[k][k];
    for (int c = 0; c < 38; ++c) A[k][c] *= rp;
    for (int r = 0; r < 19; ++r) {
      if (r == k) continue;
      double f = A[r][k];
      for (int c = 0; c < 38; ++c) A[r][c] -= f * A[k][c];
    }
  }
  WMat wm = {};
  for (int i = 0; i < 19; ++i)
    for (int j = 0; j < 16; ++j)
      wm.w[i][j] = (float)(A[i][19 + j] * (i < 16 ? 0.69314718055994530942 : 1.0));
  return wm;
}

__device__ __constant__ WMat WM = build_wm();

__device__ __forceinline__ float fast_log2(float x) {
#if __has_builtin(__builtin_amdgcn_logf)
  return __builtin_amdgcn_logf(x);
#else
  return __log2f(x);
#endif
}

// ---------------------------------------------------------------------------
// Fused kernel, 2 px/thread, software-pipelined coefficient loads.
// Stage 1: block's BGRP x 38 coefficients -> LDS.
// Stage 2: batch loop fully unrolled with double-buffered q[2][10]: batch
// bi+1's 10 ds_read_b128 are issued BEFORE batch bi's FMA block, so the
// lgkmcnt wait for them retires under ~150 cycles of independent FMAs.
// All q indexing is compile-time (full unroll) to keep buffers in VGPRs.
// ---------------------------------------------------------------------------
__global__ __launch_bounds__(256) void tps_fused_kernel(
    const float* __restrict__ sp, float* __restrict__ out) {
  __shared__ float lc[BGRP][40];   // 40-float row stride -> 16B-aligned rows
  const int b0 = blockIdx.y * BGRP;

  // ---- stage 1: coefficients for this block's batches -> LDS ----
  for (int e = threadIdx.x; e < BGRP * 38; e += 256) {
    const int bi = e / 38;
    const int idx = e - bi * 38;
    const int row = idx >> 1, d = idx & 1;     // coeff row 0..18, dim x/y
    const float* s = sp + (b0 + bi) * 32 + d;
    float acc = 0.0f;
#pragma unroll
    for (int j = 0; j < 16; ++j) acc = fmaf(WM.w[row][j], s[2 * j], acc);
    lc[bi][idx] = acc;
  }

  // ---- batch-independent pixel geometry (2 adjacent px, same row) ----
  const int n0 = (blockIdx.x * 256 + threadIdx.x) * 2;
  const int ix = n0 & (WW - 1);
  const int iy = n0 >> 9;
  const float step = 2.0f / 511.0f;
  const float gy = -1.0f + iy * step;
  const v2f gxv = {-1.0f + ix * step, -1.0f + (ix + 1) * step};
  const float Xc[4] = {-1.0f, -1.0f / 3.0f, 1.0f / 3.0f, 1.0f};

  float dy2[4];
#pragma unroll
  for (int j = 0; j < 4; ++j) { float t = gy - Xc[j]; dy2[j] = t * t; }

  v2f dxp[4];
#pragma unroll
  for (int i = 0; i < 4; ++i) {
    v2f t = gxv - Xc[i];
    dxp[i] = t * t + 1e-6f;   // eps folded here (dy2 has none)
  }

  // RBF basis, pixel-pair packed: u2[k] = {u_k(px0), u_k(px1)}
  v2f u2[16];
#pragma unroll
  for (int k = 0; k < 16; ++k) {
    v2f t = dxp[k >> 2] + dy2[k & 3];                   // pk_add
    u2[k] = t * (v2f){fast_log2(t.x), fast_log2(t.y)};  // 2 logs + pk_mul
  }

  __syncthreads();

  // ---- stage 2: fully-unrolled batch loop, double-buffered coeffs ----
  float* op = out + (size_t)((size_t)b0 * HW + n0) * 2;
  v4f q[2][10];
  {
    const v4f* c4 = (const v4f*)lc[0];
#pragma unroll
    for (int i = 0; i < 10; ++i) q[0][i] = c4[i];       // prologue: batch 0
  }

#pragma unroll
  for (int bi = 0; bi < BGRP; ++bi) {
    // prefetch batch bi+1 coeffs (issued before this batch's FMAs)
    if (bi + 1 < BGRP) {
      const v4f* c4 = (const v4f*)lc[bi + 1];
#pragma unroll
      for (int i = 0; i < 10; ++i) q[(bi + 1) & 1][i] = c4[i];
    }
#define CQ(i) (q[bi & 1][(i) >> 2][(i) & 3])            // compile-time after unroll

    v2f accx = CQ(32) + gxv * CQ(34) + gy * CQ(36);     // {x(px0), x(px1)}
    v2f accy = CQ(33) + gxv * CQ(35) + gy * CQ(37);
#pragma unroll
    for (int k = 0; k < 16; ++k) {
      accx += u2[k] * CQ(2 * k);
      accy += u2[k] * CQ(2 * k + 1);
    }
#undef CQ

    v4f v = {accx.x, accy.x, accx.y, accy.y};
    *(v4f*)op = v;
    op += (size_t)HW * 2;
  }
}

extern "C" void kernel_launch(void* const* d_in, const int* in_sizes, int n_in,
                              void* d_out, int out_size, void* d_ws, size_t ws_size,
                              hipStream_t stream) {
  const float* sp = (const float*)d_in[0];   // [B, K, 2] fp32
  float* out = (float*)d_out;                // [B, H, W, 2] fp32
  (void)d_ws; (void)ws_size;

  dim3 grid(HW / 512, BB / BGRP);            // 512 px per block x, 4 batch-groups y
  tps_fused_kernel<<<grid, 256, 0, stream>>>(sp, out);
}